// Round 7
// baseline (158.183 us; speedup 1.0000x reference)
//
#include <hip/hip_runtime.h>
#include <math.h>

#define NN 100000
#define FIN 256
#define D1 64
#define C2 47
#define S2 48                       // padded layer-2 width (3 x 16)
#define PREPB 76                    // (256*64 + 64*48)/256
#define NBKT 391                    // ceil(NN/256) buckets of 256 nodes
#define CAP 4096                    // capacity per bucket (avg 3070, max ~3350)
#define EPB 4096                    // edges per bucketing block

typedef unsigned short u16;
typedef unsigned int u32;
typedef __attribute__((ext_vector_type(8))) short short8;
typedef __attribute__((ext_vector_type(4))) float floatx4;

__device__ __forceinline__ u16 f2b(float f) {        // fp32 -> bf16 RNE
    union { float f; unsigned u; } v; v.f = f;
    unsigned r = v.u + 0x7FFF + ((v.u >> 16) & 1);
    return (u16)(r >> 16);
}
__device__ __forceinline__ float b2f_lo(u32 p) { union { unsigned u; float f; } v; v.u = p << 16; return v.f; }
__device__ __forceinline__ float b2f_hi(u32 p) { union { unsigned u; float f; } v; v.u = p & 0xFFFF0000u; return v.f; }

// ---- launch 1: W1/W2 transpose+convert (blocks 0..75) + edge bucketing ----
// bucket = dst >> 8 (391 buckets x 256 nodes). Packed edge: src | dstLocal<<17.
__global__ __launch_bounds__(256) void k_prep_bucket(
    const float* __restrict__ W1, const float* __restrict__ W2,
    u16* __restrict__ W1t, u16* __restrict__ W2t,
    const int* __restrict__ src, const int* __restrict__ dst, int E,
    int* __restrict__ bucketCnt, u32* __restrict__ ebuf)
{
    int b = blockIdx.x;
    if (b < PREPB) {
        int i = b * 256 + threadIdx.x;
        if (i < FIN * D1) {                     // W1t[c][k] = bf16(W1[k][c])
            int c = i >> 8, k = i & 255;
            W1t[i] = f2b(W1[k * D1 + c]);
        } else if (i < FIN * D1 + D1 * S2) {    // W2t[c][k], zero-padded col 47
            int j = i - FIN * D1;
            int c = j >> 6, k = j & 63;
            W2t[j] = (c < C2) ? f2b(W2[k * C2 + c]) : (u16)0;
        }
        return;
    }
    __shared__ int hist[NBKT];
    __shared__ int base[NBKT];
    const int t = threadIdx.x;
    const int blk = b - PREPB;
    for (int i = t; i < NBKT; i += 256) hist[i] = 0;
    __syncthreads();

    int e0 = blk * EPB + t;
    u32 pk[16]; int bk[16], tk[16];
    #pragma unroll
    for (int j = 0; j < 16; ++j) {
        int e = e0 + j * 256;
        bk[j] = -1;
        if (e < E) {
            int d = dst[e];
            bk[j] = d >> 8;
            pk[j] = (u32)src[e] | ((u32)(d & 255) << 17);
            tk[j] = atomicAdd(&hist[bk[j]], 1);
        }
    }
    __syncthreads();
    for (int i = t; i < NBKT; i += 256)
        base[i] = hist[i] ? atomicAdd(&bucketCnt[i], hist[i]) : 0;
    __syncthreads();
    #pragma unroll
    for (int j = 0; j < 16; ++j)
        if (bk[j] >= 0)
            ebuf[(size_t)bk[j] * CAP + base[bk[j]] + tk[j]] = pk[j];
}

// ---- launch 2: fused {per-bucket CSR ptr + dinv + colidx fill} + gemm1 ----
// gemm1 writes UNSCALED h1 = bf16(X @ W1)  (no dinv dependency -> safe fusion).
__global__ __launch_bounds__(256) void k_csrfill_gemm1(
    const int* __restrict__ bucketCnt, const u32* __restrict__ ebuf,
    int* __restrict__ rowptr, float* __restrict__ dinv, int* __restrict__ colidx,
    const float* __restrict__ x, const u16* __restrict__ W1t,
    u16* __restrict__ h1b, int E)
{
    __shared__ short As[2][64 * 40];   // gemm staging; aliased by CSR branch
    __shared__ short Bs[2][64 * 40];
    int b = blockIdx.x;
    const int t = threadIdx.x;
    if (b < NBKT) {
        int* sd   = (int*)&As[0][0];
        int* hist = sd + 256;
        int* cur  = hist + 256;
        // ebase = sum bucketCnt[0..b-1]
        int v = ((t < b) ? bucketCnt[t] : 0) + ((t + 256 < b) ? bucketCnt[t + 256] : 0);
        sd[t] = v; __syncthreads();
        for (int off = 128; off; off >>= 1) {
            if (t < off) sd[t] += sd[t + off];
            __syncthreads();
        }
        int ebase = sd[0];
        __syncthreads();

        hist[t] = 0;
        __syncthreads();
        const int cnt = bucketCnt[b];
        const u32* eb = ebuf + (size_t)b * CAP;
        for (int i = t; i < cnt; i += 256)
            atomicAdd(&hist[eb[i] >> 17], 1);
        __syncthreads();

        int h = hist[t];
        sd[t] = h; __syncthreads();
        for (int off = 1; off < 256; off <<= 1) {
            int u = (t >= off) ? sd[t - off] : 0;
            __syncthreads();
            sd[t] += u;
            __syncthreads();
        }
        int start = ebase + sd[t] - h;
        int node = b * 256 + t;
        if (node <= NN) rowptr[node] = start;
        if (node < NN) dinv[node] = rsqrtf((float)h + 1.0f);
        cur[t] = start;
        __syncthreads();

        for (int i = t; i < cnt; i += 256) {
            u32 p = eb[i];
            int pos = atomicAdd(&cur[p >> 17], 1);
            colidx[pos] = p & 0x1FFFF;
        }
        return;
    }
    const int bm = (b - NBKT) * 64;
    const int w = t >> 6, lane = t & 63;
    const int arow = t >> 2;          // 0..63
    const int ak0 = (t & 3) * 8;      // 0,8,16,24

    floatx4 acc[4] = {};
    const int gr = bm + arow;
    const bool rowok = gr < NN;
    const float* xrow = x + (size_t)(rowok ? gr : 0) * FIN + ak0;

    float4 v0 = make_float4(0.f,0.f,0.f,0.f), v1 = v0;
    if (rowok) { v0 = *(const float4*)(xrow); v1 = *(const float4*)(xrow + 4); }
    short8 wv = *(const short8*)(W1t + arow * FIN + ak0);
    {
        short8 av;
        av[0]=(short)f2b(v0.x); av[1]=(short)f2b(v0.y); av[2]=(short)f2b(v0.z); av[3]=(short)f2b(v0.w);
        av[4]=(short)f2b(v1.x); av[5]=(short)f2b(v1.y); av[6]=(short)f2b(v1.z); av[7]=(short)f2b(v1.w);
        *(short8*)(&As[0][arow * 40 + ak0]) = av;
        *(short8*)(&Bs[0][arow * 40 + ak0]) = wv;
    }
    __syncthreads();

    int cb_ = 0;
    for (int kt = 32; kt <= FIN; kt += 32) {
        const bool more = kt < FIN;
        float4 n0, n1; short8 nw;
        if (more) {
            if (rowok) { n0 = *(const float4*)(xrow + kt); n1 = *(const float4*)(xrow + kt + 4); }
            else { n0 = make_float4(0.f,0.f,0.f,0.f); n1 = n0; }
            nw = *(const short8*)(W1t + arow * FIN + kt + ak0);
        }
        short8 af = *(const short8*)(&As[cb_][(w * 16 + (lane & 15)) * 40 + (lane >> 4) * 8]);
        #pragma unroll
        for (int cb = 0; cb < 4; ++cb) {
            short8 bv = *(const short8*)(&Bs[cb_][(cb * 16 + (lane & 15)) * 40 + (lane >> 4) * 8]);
            acc[cb] = __builtin_amdgcn_mfma_f32_16x16x32_bf16(af, bv, acc[cb], 0, 0, 0);
        }
        if (!more) break;
        short8 av;
        av[0]=(short)f2b(n0.x); av[1]=(short)f2b(n0.y); av[2]=(short)f2b(n0.z); av[3]=(short)f2b(n0.w);
        av[4]=(short)f2b(n1.x); av[5]=(short)f2b(n1.y); av[6]=(short)f2b(n1.z); av[7]=(short)f2b(n1.w);
        *(short8*)(&As[cb_ ^ 1][arow * 40 + ak0]) = av;
        *(short8*)(&Bs[cb_ ^ 1][arow * 40 + ak0]) = nw;
        __syncthreads();
        cb_ ^= 1;
    }

    #pragma unroll
    for (int cb = 0; cb < 4; ++cb) {
        #pragma unroll
        for (int r = 0; r < 4; ++r) {
            int grow = bm + w * 16 + (lane >> 4) * 4 + r;
            if (grow < NN)
                h1b[(size_t)grow * D1 + cb * 16 + (lane & 15)] = f2b(acc[cb][r]);
        }
    }
}

// ---- launch 3: gather layer 1 (dinv[s]-weighted, into LDS) + gemm2 + scale ----
// 16-lane groups, uint2 (8B) loads: 4 nodes in flight per wave, 8-deep unroll.
__global__ __launch_bounds__(256) void k_gather_gemm2(
    const int* __restrict__ rowptr, const int* __restrict__ colidx,
    const float* __restrict__ dinv, const u16* __restrict__ h1b,
    const float* __restrict__ b1, const u16* __restrict__ W2t,
    u16* __restrict__ hs2)
{
    __shared__ short As[2][64 * 40];   // [kt][row][k%32], stride 40
    __shared__ short Bs[2][48 * 40];
    const int t = threadIdx.x;
    const int bm = blockIdx.x * 64;
    const int w = t >> 6;
    const int g16 = (t >> 4) & 3;
    const int l16 = t & 15;

    for (int s = t; s < 384; s += 256) {
        int kt = s / 192, rem = s - kt * 192;
        int r = rem >> 2, j = rem & 3;
        *(short8*)(&Bs[kt][r * 40 + j * 8]) =
            *(const short8*)(W2t + r * D1 + kt * 32 + j * 8);
    }

    {
        float4 bb = *(const float4*)(b1 + 4 * l16);
        const int col = 4 * l16;
        const int kth = col >> 5;
        const int cs  = col & 31;
        #pragma unroll 1
        for (int i = 0; i < 4; ++i) {
            int rl = w * 16 + g16 * 4 + i;
            int node = bm + rl;
            if (node >= NN) break;
            int beg = rowptr[node], end = rowptr[node + 1];
            float dd = dinv[node];
            uint2 sp = *((const uint2*)(h1b + (size_t)node * D1) + l16);
            float ac[4][4];
            ac[0][0] = dd * b2f_lo(sp.x); ac[0][1] = dd * b2f_hi(sp.x);
            ac[0][2] = dd * b2f_lo(sp.y); ac[0][3] = dd * b2f_hi(sp.y);
            #pragma unroll
            for (int st = 1; st < 4; ++st)
                ac[st][0] = ac[st][1] = ac[st][2] = ac[st][3] = 0.f;
            int e = beg;
            for (; e + 8 <= end; e += 8) {
                int c[8]; float ds[8]; uint2 p[8];
                #pragma unroll
                for (int j = 0; j < 8; ++j) c[j] = colidx[e + j];
                #pragma unroll
                for (int j = 0; j < 8; ++j) ds[j] = dinv[c[j]];
                #pragma unroll
                for (int j = 0; j < 8; ++j)
                    p[j] = *((const uint2*)(h1b + (size_t)c[j] * D1) + l16);
                #pragma unroll
                for (int j = 0; j < 8; ++j) {
                    ac[j & 3][0] += ds[j] * b2f_lo(p[j].x);
                    ac[j & 3][1] += ds[j] * b2f_hi(p[j].x);
                    ac[j & 3][2] += ds[j] * b2f_lo(p[j].y);
                    ac[j & 3][3] += ds[j] * b2f_hi(p[j].y);
                }
            }
            for (; e < end; ++e) {
                int c0 = colidx[e];
                float d0 = dinv[c0];
                uint2 p0 = *((const uint2*)(h1b + (size_t)c0 * D1) + l16);
                ac[0][0] += d0 * b2f_lo(p0.x); ac[0][1] += d0 * b2f_hi(p0.x);
                ac[0][2] += d0 * b2f_lo(p0.y); ac[0][3] += d0 * b2f_hi(p0.y);
            }
            float fv0 = (ac[0][0] + ac[1][0]) + (ac[2][0] + ac[3][0]);
            float fv1 = (ac[0][1] + ac[1][1]) + (ac[2][1] + ac[3][1]);
            float fv2 = (ac[0][2] + ac[1][2]) + (ac[2][2] + ac[3][2]);
            float fv3 = (ac[0][3] + ac[1][3]) + (ac[2][3] + ac[3][3]);
            float r0 = fmaxf(fmaf(dd, fv0, bb.x), 0.f);
            float r1 = fmaxf(fmaf(dd, fv1, bb.y), 0.f);
            float r2 = fmaxf(fmaf(dd, fv2, bb.z), 0.f);
            float r3 = fmaxf(fmaf(dd, fv3, bb.w), 0.f);
            u32 lo = (u32)f2b(r0) | ((u32)f2b(r1) << 16);
            u32 hi = (u32)f2b(r2) | ((u32)f2b(r3) << 16);
            *(u32*)(&As[kth][rl * 40 + cs]) = lo;
            *(u32*)(&As[kth][rl * 40 + cs + 2]) = hi;
        }
    }
    __syncthreads();

    const int lane = t & 63;
    floatx4 acc[3] = {};
    #pragma unroll
    for (int kt = 0; kt < 2; ++kt) {
        short8 af = *(const short8*)(&As[kt][(w * 16 + (lane & 15)) * 40 + (lane >> 4) * 8]);
        #pragma unroll
        for (int cb = 0; cb < 3; ++cb) {
            short8 bv = *(const short8*)(&Bs[kt][(cb * 16 + (lane & 15)) * 40 + (lane >> 4) * 8]);
            acc[cb] = __builtin_amdgcn_mfma_f32_16x16x32_bf16(af, bv, acc[cb], 0, 0, 0);
        }
    }

    #pragma unroll
    for (int cb = 0; cb < 3; ++cb) {
        #pragma unroll
        for (int r = 0; r < 4; ++r) {
            int grow = bm + w * 16 + (lane >> 4) * 4 + r;
            if (grow < NN) {
                float v = acc[cb][r] * dinv[grow];
                hs2[(size_t)grow * S2 + cb * 16 + (lane & 15)] = f2b(v);
            }
        }
    }
}

// ---- launch 4: gather layer 2 + log_softmax: 16-lane groups (12 active, u64) ----
__global__ __launch_bounds__(256) void k_gather47_sm(const int* __restrict__ rowptr,
                                                     const int* __restrict__ colidx,
                                                     const float* __restrict__ dinv,
                                                     const u16* __restrict__ hs,
                                                     const float* __restrict__ b2,
                                                     float* __restrict__ out) {
    int node = blockIdx.x * 16 + (threadIdx.x >> 4);
    int l16 = threadIdx.x & 15;
    if (node >= NN) return;
    bool act = l16 < 12;
    int lc = act ? l16 : 0;
    int beg = rowptr[node], end = rowptr[node + 1];
    uint2 sp = *((const uint2*)(hs + (size_t)node * S2) + lc);
    float ac[4][4];
    ac[0][0] = b2f_lo(sp.x); ac[0][1] = b2f_hi(sp.x);
    ac[0][2] = b2f_lo(sp.y); ac[0][3] = b2f_hi(sp.y);
    #pragma unroll
    for (int st = 1; st < 4; ++st)
        ac[st][0] = ac[st][1] = ac[st][2] = ac[st][3] = 0.f;
    int e = beg;
    for (; e + 8 <= end; e += 8) {
        int c[8]; uint2 p[8];
        #pragma unroll
        for (int j = 0; j < 8; ++j) c[j] = colidx[e + j];
        #pragma unroll
        for (int j = 0; j < 8; ++j)
            p[j] = *((const uint2*)(hs + (size_t)c[j] * S2) + lc);
        #pragma unroll
        for (int j = 0; j < 8; ++j) {
            ac[j & 3][0] += b2f_lo(p[j].x);
            ac[j & 3][1] += b2f_hi(p[j].x);
            ac[j & 3][2] += b2f_lo(p[j].y);
            ac[j & 3][3] += b2f_hi(p[j].y);
        }
    }
    for (; e < end; ++e) {
        uint2 p0 = *((const uint2*)(hs + (size_t)colidx[e] * S2) + lc);
        ac[0][0] += b2f_lo(p0.x); ac[0][1] += b2f_hi(p0.x);
        ac[0][2] += b2f_lo(p0.y); ac[0][3] += b2f_hi(p0.y);
    }
    float dd = dinv[node];
    float val[4];
    float m = -INFINITY;
    #pragma unroll
    for (int k = 0; k < 4; ++k) {
        int fe = 4 * l16 + k;
        float f = (ac[0][k] + ac[1][k]) + (ac[2][k] + ac[3][k]);
        bool valid = act && (fe < C2);
        val[k] = valid ? fmaf(dd, f, b2[valid ? fe : 0]) : -INFINITY;
        m = fmaxf(m, val[k]);
    }
    #pragma unroll
    for (int off = 1; off < 16; off <<= 1) m = fmaxf(m, __shfl_xor(m, off));
    float ex = 0.f;
    #pragma unroll
    for (int k = 0; k < 4; ++k)
        if (val[k] > -INFINITY) ex += expf(val[k] - m);
    #pragma unroll
    for (int off = 1; off < 16; off <<= 1) ex += __shfl_xor(ex, off);
    float ls = m + logf(ex);
    #pragma unroll
    for (int k = 0; k < 4; ++k) {
        int fe = 4 * l16 + k;
        if (act && fe < C2) out[(size_t)node * C2 + fe] = val[k] - ls;
    }
}

extern "C" void kernel_launch(void* const* d_in, const int* in_sizes, int n_in,
                              void* d_out, int out_size, void* d_ws, size_t ws_size,
                              hipStream_t stream) {
    const float* x  = (const float*)d_in[0];
    const int*   ei = (const int*)d_in[1];
    const float* W1 = (const float*)d_in[2];
    const float* b1 = (const float*)d_in[3];
    const float* W2 = (const float*)d_in[4];
    const float* b2 = (const float*)d_in[5];
    float* out = (float*)d_out;

    const int E = in_sizes[1] / 2;
    const int* src = ei;
    const int* dst = ei + E;

    char* ws = (char*)d_ws;
    float* dinv      = (float*)(ws);               // 400 KB
    int*   bucketCnt = (int*)(ws + 0x80000);       // 1.6 KB
    int*   rowptr    = (int*)(ws + 0x100000);      // 400 KB + 4
    u16*   W1t       = (u16*)(ws + 0x180000);      // 32 KB
    u16*   W2t       = (u16*)(ws + 0x189000);      // 6 KB
    u32*   ebuf      = (u32*)(ws + 0x200000);      // 6.4 MB (391*4096*4)
    int*   colidx    = (int*)(ws + 0x900000);      // 4.8 MB
    u16*   h1b       = (u16*)(ws + 0xE00000);      // 12.8 MB (unscaled X@W1)
    u16*   hs2       = (u16*)(ws + 0x1B00000);     // 9.6 MB (dinv-scaled h1@W2)

    const int nBk1 = (E + EPB - 1) / EPB;          // 293 bucketing blocks
    const int gb1  = (NN + 63) / 64;               // 1563 gemm blocks

    hipMemsetAsync(bucketCnt, 0, NBKT * sizeof(int), stream);
    k_prep_bucket<<<PREPB + nBk1, 256, 0, stream>>>(W1, W2, W1t, W2t, src, dst, E,
                                                    bucketCnt, ebuf);
    k_csrfill_gemm1<<<NBKT + gb1, 256, 0, stream>>>(bucketCnt, ebuf, rowptr, dinv,
                                                    colidx, x, W1t, h1b, E);
    k_gather_gemm2<<<gb1, 256, 0, stream>>>(rowptr, colidx, dinv, h1b, b1, W2t, hs2);
    k_gather47_sm<<<(NN + 15) / 16, 256, 0, stream>>>(rowptr, colidx, dinv, hs2, b2, out);
}

// Round 8
// 134.758 us; speedup vs baseline: 1.1738x; 1.1738x over previous
//
#include <hip/hip_runtime.h>
#include <math.h>

#define NN 100000
#define FIN 256
#define D1 64
#define C2 47
#define S2 48                       // padded layer-2 width (3 x 16)
#define PREPB 76                    // (256*64 + 64*48)/256
#define NBKT 391                    // ceil(NN/256) buckets of 256 nodes
#define CAP 4096                    // capacity per bucket (avg 3070)
#define EPB 4096                    // edges per bucketing block

typedef unsigned short u16;
typedef unsigned int u32;
typedef __attribute__((ext_vector_type(8))) short short8;
typedef __attribute__((ext_vector_type(4))) float floatx4;

__device__ __forceinline__ u16 f2b(float f) {        // fp32 -> bf16 RNE
    union { float f; unsigned u; } v; v.f = f;
    unsigned r = v.u + 0x7FFF + ((v.u >> 16) & 1);
    return (u16)(r >> 16);
}
__device__ __forceinline__ float b2f_lo(u32 p) { union { unsigned u; float f; } v; v.u = p << 16; return v.f; }
__device__ __forceinline__ float b2f_hi(u32 p) { union { unsigned u; float f; } v; v.u = p & 0xFFFF0000u; return v.f; }

// ---- launch 1: W1/W2 transpose+convert (blocks 0..75) + edge bucketing ----
__global__ __launch_bounds__(256) void k_prep_bucket(
    const float* __restrict__ W1, const float* __restrict__ W2,
    u16* __restrict__ W1t, u16* __restrict__ W2t,
    const int* __restrict__ src, const int* __restrict__ dst, int E,
    int* __restrict__ bucketCnt, u32* __restrict__ ebuf)
{
    int b = blockIdx.x;
    if (b < PREPB) {
        int i = b * 256 + threadIdx.x;
        if (i < FIN * D1) {                     // W1t[c][k] = bf16(W1[k][c])
            int c = i >> 8, k = i & 255;
            W1t[i] = f2b(W1[k * D1 + c]);
        } else if (i < FIN * D1 + D1 * S2) {    // W2t[c][k], zero-padded col 47
            int j = i - FIN * D1;
            int c = j >> 6, k = j & 63;
            W2t[j] = (c < C2) ? f2b(W2[k * C2 + c]) : (u16)0;
        }
        return;
    }
    __shared__ int hist[NBKT];
    __shared__ int base[NBKT];
    const int t = threadIdx.x;
    const int blk = b - PREPB;
    for (int i = t; i < NBKT; i += 256) hist[i] = 0;
    __syncthreads();

    int e0 = blk * EPB + t;
    u32 pk[16]; int bk[16], tk[16];
    #pragma unroll
    for (int j = 0; j < 16; ++j) {
        int e = e0 + j * 256;
        bk[j] = -1;
        if (e < E) {
            int d = dst[e];
            bk[j] = d >> 8;
            pk[j] = (u32)src[e] | ((u32)(d & 255) << 17);
            tk[j] = atomicAdd(&hist[bk[j]], 1);
        }
    }
    __syncthreads();
    for (int i = t; i < NBKT; i += 256)
        base[i] = hist[i] ? atomicAdd(&bucketCnt[i], hist[i]) : 0;
    __syncthreads();
    #pragma unroll
    for (int j = 0; j < 16; ++j)
        if (bk[j] >= 0)
            ebuf[(size_t)bk[j] * CAP + base[bk[j]] + tk[j]] = pk[j];
}

// ---- launch 2: per-bucket node histogram + scan -> rowptr, dinv ----
__global__ __launch_bounds__(256) void k_csr_ptr(const int* __restrict__ bucketCnt,
                                                 const u32* __restrict__ ebuf,
                                                 int* __restrict__ rowptr,
                                                 float* __restrict__ dinv, int E) {
    __shared__ int sd[256];
    __shared__ int hist[256];
    const int b = blockIdx.x, t = threadIdx.x;
    int v = ((t < b) ? bucketCnt[t] : 0) + ((t + 256 < b) ? bucketCnt[t + 256] : 0);
    sd[t] = v; __syncthreads();
    for (int off = 128; off; off >>= 1) {
        if (t < off) sd[t] += sd[t + off];
        __syncthreads();
    }
    int ebase = sd[0];
    __syncthreads();

    hist[t] = 0;
    __syncthreads();
    const int cnt = bucketCnt[b];
    const u32* eb = ebuf + (size_t)b * CAP;
    for (int i = t; i < cnt; i += 256)
        atomicAdd(&hist[eb[i] >> 17], 1);
    __syncthreads();

    int h = hist[t];
    sd[t] = h; __syncthreads();
    for (int off = 1; off < 256; off <<= 1) {
        int u = (t >= off) ? sd[t - off] : 0;
        __syncthreads();
        sd[t] += u;
        __syncthreads();
    }
    int node = b * 256 + t;
    if (node <= NN) rowptr[node] = ebase + sd[t] - h;
    if (node < NN) dinv[node] = rsqrtf((float)h + 1.0f);
    if (b == 0 && t == 0) rowptr[NN] = E;
}

// ---- launch 3: bucket-local CSR fill (blocks < NBKT) + gemm1 MFMA ----
// gemm1: hs1[r][c] = bf16( dinv[r] * sum_k x[r][k]*W1[k][c] ), ping-pong LDS.
__global__ __launch_bounds__(256) void k_fill_gemm1(
    const int* __restrict__ bucketCnt, const u32* __restrict__ ebuf,
    const int* __restrict__ rowptr, int* __restrict__ colidx,
    const float* __restrict__ x, const u16* __restrict__ W1t,
    const float* __restrict__ dinv, u16* __restrict__ hs1)
{
    int b = blockIdx.x;
    const int t = threadIdx.x;
    if (b < NBKT) {
        __shared__ int cur[256];
        int node = b * 256 + t;
        cur[t] = (node < NN) ? rowptr[node] : 0;
        __syncthreads();
        const int cnt = bucketCnt[b];
        const u32* eb = ebuf + (size_t)b * CAP;
        for (int i = t; i < cnt; i += 256) {
            u32 p = eb[i];
            int pos = atomicAdd(&cur[p >> 17], 1);
            colidx[pos] = p & 0x1FFFF;
        }
        return;
    }
    __shared__ short As[2][64 * 40];   // [buf][row][k], stride 40
    __shared__ short Bs[2][64 * 40];   // [buf][col][k]
    const int bm = (b - NBKT) * 64;
    const int w = t >> 6, lane = t & 63;
    const int arow = t >> 2;          // 0..63
    const int ak0 = (t & 3) * 8;      // 0,8,16,24

    floatx4 acc[4] = {};
    const int gr = bm + arow;
    const bool rowok = gr < NN;
    const float* xrow = x + (size_t)(rowok ? gr : 0) * FIN + ak0;

    float4 v0 = make_float4(0.f,0.f,0.f,0.f), v1 = v0;
    if (rowok) { v0 = *(const float4*)(xrow); v1 = *(const float4*)(xrow + 4); }
    short8 wv = *(const short8*)(W1t + arow * FIN + ak0);
    {
        short8 av;
        av[0]=(short)f2b(v0.x); av[1]=(short)f2b(v0.y); av[2]=(short)f2b(v0.z); av[3]=(short)f2b(v0.w);
        av[4]=(short)f2b(v1.x); av[5]=(short)f2b(v1.y); av[6]=(short)f2b(v1.z); av[7]=(short)f2b(v1.w);
        *(short8*)(&As[0][arow * 40 + ak0]) = av;
        *(short8*)(&Bs[0][arow * 40 + ak0]) = wv;
    }
    __syncthreads();

    int cb_ = 0;
    for (int kt = 32; kt <= FIN; kt += 32) {
        const bool more = kt < FIN;
        float4 n0, n1; short8 nw;
        if (more) {
            if (rowok) { n0 = *(const float4*)(xrow + kt); n1 = *(const float4*)(xrow + kt + 4); }
            else { n0 = make_float4(0.f,0.f,0.f,0.f); n1 = n0; }
            nw = *(const short8*)(W1t + arow * FIN + kt + ak0);
        }
        short8 af = *(const short8*)(&As[cb_][(w * 16 + (lane & 15)) * 40 + (lane >> 4) * 8]);
        #pragma unroll
        for (int cb = 0; cb < 4; ++cb) {
            short8 bv = *(const short8*)(&Bs[cb_][(cb * 16 + (lane & 15)) * 40 + (lane >> 4) * 8]);
            acc[cb] = __builtin_amdgcn_mfma_f32_16x16x32_bf16(af, bv, acc[cb], 0, 0, 0);
        }
        if (!more) break;
        short8 av;
        av[0]=(short)f2b(n0.x); av[1]=(short)f2b(n0.y); av[2]=(short)f2b(n0.z); av[3]=(short)f2b(n0.w);
        av[4]=(short)f2b(n1.x); av[5]=(short)f2b(n1.y); av[6]=(short)f2b(n1.z); av[7]=(short)f2b(n1.w);
        *(short8*)(&As[cb_ ^ 1][arow * 40 + ak0]) = av;
        *(short8*)(&Bs[cb_ ^ 1][arow * 40 + ak0]) = nw;
        __syncthreads();
        cb_ ^= 1;
    }

    #pragma unroll
    for (int cb = 0; cb < 4; ++cb) {
        #pragma unroll
        for (int r = 0; r < 4; ++r) {
            int grow = bm + w * 16 + (lane >> 4) * 4 + r;
            if (grow < NN) {
                float v = acc[cb][r] * dinv[grow];
                hs1[(size_t)grow * D1 + cb * 16 + (lane & 15)] = f2b(v);
            }
        }
    }
}

// ---- launch 4: gather layer 1 + gemm2 + dinv-scale epilogue ----
// 8-lane groups, uint4 (16B) loads: one wave-VMEM inst gathers 8 rows (1KB).
// 32 groups/block x 2 nodes each = 64 nodes; 4-deep edge unroll.
__global__ __launch_bounds__(256) void k_gather_gemm2(
    const int* __restrict__ rowptr, const int* __restrict__ colidx,
    const float* __restrict__ dinv, const u16* __restrict__ hs1,
    const float* __restrict__ b1, const u16* __restrict__ W2t,
    u16* __restrict__ hs2)
{
    __shared__ short As[2][64 * 40];   // [kt][row][k%32], stride 40
    __shared__ short Bs[2][48 * 40];
    const int t = threadIdx.x;
    const int bm = blockIdx.x * 64;
    const int w = t >> 6;
    const int g8 = (t >> 3) & 7;
    const int l8 = t & 7;

    for (int s = t; s < 384; s += 256) {
        int kt = s / 192, rem = s - kt * 192;
        int r = rem >> 2, j = rem & 3;
        *(short8*)(&Bs[kt][r * 40 + j * 8]) =
            *(const short8*)(W2t + r * D1 + kt * 32 + j * 8);
    }

    {
        const int col = 8 * l8;            // feats col..col+7
        const int kth = l8 >> 2;
        const int cs  = col & 31;
        float4 bbl = *(const float4*)(b1 + col);
        float4 bbh = *(const float4*)(b1 + col + 4);
        #pragma unroll 1
        for (int i = 0; i < 2; ++i) {
            int rl = w * 16 + g8 * 2 + i;
            int node = bm + rl;
            if (node >= NN) break;
            int beg = rowptr[node], end = rowptr[node + 1];
            uint4 sp = *((const uint4*)(hs1 + (size_t)node * D1) + l8);   // self
            float a0=b2f_lo(sp.x), a1=b2f_hi(sp.x), a2=b2f_lo(sp.y), a3=b2f_hi(sp.y);
            float a4=b2f_lo(sp.z), a5=b2f_hi(sp.z), a6=b2f_lo(sp.w), a7=b2f_hi(sp.w);
            float c0=0.f,c1=0.f,c2=0.f,c3=0.f,c4=0.f,c5=0.f,c6=0.f,c7=0.f;
            int e = beg;
            for (; e + 4 <= end; e += 4) {
                int s0 = colidx[e+0], s1 = colidx[e+1], s2 = colidx[e+2], s3 = colidx[e+3];
                uint4 p0 = *((const uint4*)(hs1 + (size_t)s0 * D1) + l8);
                uint4 p1 = *((const uint4*)(hs1 + (size_t)s1 * D1) + l8);
                uint4 p2 = *((const uint4*)(hs1 + (size_t)s2 * D1) + l8);
                uint4 p3 = *((const uint4*)(hs1 + (size_t)s3 * D1) + l8);
                a0+=b2f_lo(p0.x); a1+=b2f_hi(p0.x); a2+=b2f_lo(p0.y); a3+=b2f_hi(p0.y);
                a4+=b2f_lo(p0.z); a5+=b2f_hi(p0.z); a6+=b2f_lo(p0.w); a7+=b2f_hi(p0.w);
                c0+=b2f_lo(p1.x); c1+=b2f_hi(p1.x); c2+=b2f_lo(p1.y); c3+=b2f_hi(p1.y);
                c4+=b2f_lo(p1.z); c5+=b2f_hi(p1.z); c6+=b2f_lo(p1.w); c7+=b2f_hi(p1.w);
                a0+=b2f_lo(p2.x); a1+=b2f_hi(p2.x); a2+=b2f_lo(p2.y); a3+=b2f_hi(p2.y);
                a4+=b2f_lo(p2.z); a5+=b2f_hi(p2.z); a6+=b2f_lo(p2.w); a7+=b2f_hi(p2.w);
                c0+=b2f_lo(p3.x); c1+=b2f_hi(p3.x); c2+=b2f_lo(p3.y); c3+=b2f_hi(p3.y);
                c4+=b2f_lo(p3.z); c5+=b2f_hi(p3.z); c6+=b2f_lo(p3.w); c7+=b2f_hi(p3.w);
            }
            for (; e < end; ++e) {
                uint4 p0 = *((const uint4*)(hs1 + (size_t)colidx[e] * D1) + l8);
                a0+=b2f_lo(p0.x); a1+=b2f_hi(p0.x); a2+=b2f_lo(p0.y); a3+=b2f_hi(p0.y);
                a4+=b2f_lo(p0.z); a5+=b2f_hi(p0.z); a6+=b2f_lo(p0.w); a7+=b2f_hi(p0.w);
            }
            float dd = dinv[node];
            float r0 = fmaxf(fmaf(dd, a0 + c0, bbl.x), 0.f);
            float r1 = fmaxf(fmaf(dd, a1 + c1, bbl.y), 0.f);
            float r2 = fmaxf(fmaf(dd, a2 + c2, bbl.z), 0.f);
            float r3 = fmaxf(fmaf(dd, a3 + c3, bbl.w), 0.f);
            float r4 = fmaxf(fmaf(dd, a4 + c4, bbh.x), 0.f);
            float r5 = fmaxf(fmaf(dd, a5 + c5, bbh.y), 0.f);
            float r6 = fmaxf(fmaf(dd, a6 + c6, bbh.z), 0.f);
            float r7 = fmaxf(fmaf(dd, a7 + c7, bbh.w), 0.f);
            short8 pk;
            pk[0]=(short)f2b(r0); pk[1]=(short)f2b(r1); pk[2]=(short)f2b(r2); pk[3]=(short)f2b(r3);
            pk[4]=(short)f2b(r4); pk[5]=(short)f2b(r5); pk[6]=(short)f2b(r6); pk[7]=(short)f2b(r7);
            *(short8*)(&As[kth][rl * 40 + cs]) = pk;
        }
    }
    __syncthreads();

    const int lane = t & 63;
    floatx4 acc[3] = {};
    #pragma unroll
    for (int kt = 0; kt < 2; ++kt) {
        short8 af = *(const short8*)(&As[kt][(w * 16 + (lane & 15)) * 40 + (lane >> 4) * 8]);
        #pragma unroll
        for (int cb = 0; cb < 3; ++cb) {
            short8 bv = *(const short8*)(&Bs[kt][(cb * 16 + (lane & 15)) * 40 + (lane >> 4) * 8]);
            acc[cb] = __builtin_amdgcn_mfma_f32_16x16x32_bf16(af, bv, acc[cb], 0, 0, 0);
        }
    }

    #pragma unroll
    for (int cb = 0; cb < 3; ++cb) {
        #pragma unroll
        for (int r = 0; r < 4; ++r) {
            int grow = bm + w * 16 + (lane >> 4) * 4 + r;
            if (grow < NN) {
                float v = acc[cb][r] * dinv[grow];
                hs2[(size_t)grow * S2 + cb * 16 + (lane & 15)] = f2b(v);
            }
        }
    }
}

// ---- launch 5: gather layer 2 + log_softmax: 8-lane groups (6 active, uint4) ----
__global__ __launch_bounds__(256) void k_gather47_sm(const int* __restrict__ rowptr,
                                                     const int* __restrict__ colidx,
                                                     const float* __restrict__ dinv,
                                                     const u16* __restrict__ hs,
                                                     const float* __restrict__ b2,
                                                     float* __restrict__ out) {
    int node = blockIdx.x * 32 + (threadIdx.x >> 3);
    int l8 = threadIdx.x & 7;
    if (node >= NN) return;
    bool act = l8 < 6;
    int lc = act ? l8 : 0;
    int beg = rowptr[node], end = rowptr[node + 1];
    uint4 sp = *((const uint4*)(hs + (size_t)node * S2) + lc);   // self (prescaled)
    float a0=b2f_lo(sp.x), a1=b2f_hi(sp.x), a2=b2f_lo(sp.y), a3=b2f_hi(sp.y);
    float a4=b2f_lo(sp.z), a5=b2f_hi(sp.z), a6=b2f_lo(sp.w), a7=b2f_hi(sp.w);
    float c0=0.f,c1=0.f,c2=0.f,c3=0.f,c4=0.f,c5=0.f,c6=0.f,c7=0.f;
    int e = beg;
    for (; e + 4 <= end; e += 4) {
        int s0 = colidx[e+0], s1 = colidx[e+1], s2 = colidx[e+2], s3 = colidx[e+3];
        uint4 p0 = *((const uint4*)(hs + (size_t)s0 * S2) + lc);
        uint4 p1 = *((const uint4*)(hs + (size_t)s1 * S2) + lc);
        uint4 p2 = *((const uint4*)(hs + (size_t)s2 * S2) + lc);
        uint4 p3 = *((const uint4*)(hs + (size_t)s3 * S2) + lc);
        a0+=b2f_lo(p0.x); a1+=b2f_hi(p0.x); a2+=b2f_lo(p0.y); a3+=b2f_hi(p0.y);
        a4+=b2f_lo(p0.z); a5+=b2f_hi(p0.z); a6+=b2f_lo(p0.w); a7+=b2f_hi(p0.w);
        c0+=b2f_lo(p1.x); c1+=b2f_hi(p1.x); c2+=b2f_lo(p1.y); c3+=b2f_hi(p1.y);
        c4+=b2f_lo(p1.z); c5+=b2f_hi(p1.z); c6+=b2f_lo(p1.w); c7+=b2f_hi(p1.w);
        a0+=b2f_lo(p2.x); a1+=b2f_hi(p2.x); a2+=b2f_lo(p2.y); a3+=b2f_hi(p2.y);
        a4+=b2f_lo(p2.z); a5+=b2f_hi(p2.z); a6+=b2f_lo(p2.w); a7+=b2f_hi(p2.w);
        c0+=b2f_lo(p3.x); c1+=b2f_hi(p3.x); c2+=b2f_lo(p3.y); c3+=b2f_hi(p3.y);
        c4+=b2f_lo(p3.z); c5+=b2f_hi(p3.z); c6+=b2f_lo(p3.w); c7+=b2f_hi(p3.w);
    }
    for (; e < end; ++e) {
        uint4 p0 = *((const uint4*)(hs + (size_t)colidx[e] * S2) + lc);
        a0+=b2f_lo(p0.x); a1+=b2f_hi(p0.x); a2+=b2f_lo(p0.y); a3+=b2f_hi(p0.y);
        a4+=b2f_lo(p0.z); a5+=b2f_hi(p0.z); a6+=b2f_lo(p0.w); a7+=b2f_hi(p0.w);
    }
    float dd = dinv[node];
    float fv[8] = { a0+c0, a1+c1, a2+c2, a3+c3, a4+c4, a5+c5, a6+c6, a7+c7 };
    const int fb = 8 * lc;
    float val[8];
    float m = -INFINITY;
    #pragma unroll
    for (int k = 0; k < 8; ++k) {
        int fe = fb + k;
        bool valid = act && (fe < C2);
        val[k] = valid ? fmaf(dd, fv[k], b2[valid ? fe : 0]) : -INFINITY;
        m = fmaxf(m, val[k]);
    }
    #pragma unroll
    for (int off = 1; off < 8; off <<= 1) m = fmaxf(m, __shfl_xor(m, off));
    float ex = 0.f;
    #pragma unroll
    for (int k = 0; k < 8; ++k)
        if (val[k] > -INFINITY) ex += expf(val[k] - m);
    #pragma unroll
    for (int off = 1; off < 8; off <<= 1) ex += __shfl_xor(ex, off);
    float ls = m + logf(ex);
    #pragma unroll
    for (int k = 0; k < 8; ++k) {
        int fe = fb + k;
        if (act && fe < C2) out[(size_t)node * C2 + fe] = val[k] - ls;
    }
}

extern "C" void kernel_launch(void* const* d_in, const int* in_sizes, int n_in,
                              void* d_out, int out_size, void* d_ws, size_t ws_size,
                              hipStream_t stream) {
    const float* x  = (const float*)d_in[0];
    const int*   ei = (const int*)d_in[1];
    const float* W1 = (const float*)d_in[2];
    const float* b1 = (const float*)d_in[3];
    const float* W2 = (const float*)d_in[4];
    const float* b2 = (const float*)d_in[5];
    float* out = (float*)d_out;

    const int E = in_sizes[1] / 2;
    const int* src = ei;
    const int* dst = ei + E;

    char* ws = (char*)d_ws;
    float* dinv      = (float*)(ws);               // 400 KB
    int*   bucketCnt = (int*)(ws + 0x80000);       // 1.6 KB
    int*   rowptr    = (int*)(ws + 0x100000);      // 400 KB + 4
    u16*   W1t       = (u16*)(ws + 0x180000);      // 32 KB
    u16*   W2t       = (u16*)(ws + 0x189000);      // 6 KB
    u32*   ebuf      = (u32*)(ws + 0x200000);      // 6.4 MB (391*4096*4)
    int*   colidx    = (int*)(ws + 0x900000);      // 4.8 MB
    u16*   hs1       = (u16*)(ws + 0xE00000);      // 12.8 MB (dinv-prescaled X@W1)
    u16*   hs2       = (u16*)(ws + 0x1B00000);     // 9.6 MB (dinv-prescaled h1@W2)

    const int nBk1 = (E + EPB - 1) / EPB;          // 293 bucketing blocks
    const int gb1  = (NN + 63) / 64;               // 1563 gemm blocks

    hipMemsetAsync(bucketCnt, 0, NBKT * sizeof(int), stream);
    k_prep_bucket<<<PREPB + nBk1, 256, 0, stream>>>(W1, W2, W1t, W2t, src, dst, E,
                                                    bucketCnt, ebuf);
    k_csr_ptr<<<NBKT, 256, 0, stream>>>(bucketCnt, ebuf, rowptr, dinv, E);
    k_fill_gemm1<<<NBKT + gb1, 256, 0, stream>>>(bucketCnt, ebuf, rowptr, colidx,
                                                 x, W1t, dinv, hs1);
    k_gather_gemm2<<<gb1, 256, 0, stream>>>(rowptr, colidx, dinv, hs1, b1, W2t, hs2);
    k_gather47_sm<<<(NN + 31) / 32, 256, 0, stream>>>(rowptr, colidx, dinv, hs2, b2, out);
}